// Round 12
// baseline (315.021 us; speedup 1.0000x reference)
//
#include <hip/hip_runtime.h>
#include <stdint.h>

// ---------------- problem constants ----------------
#define T_    2
#define WQ_   75
#define WS_   25
#define C_    640
#define HW_   100
#define HID_  40
#define WAY_  5
#define QP_   (WQ_*HW_)     // 7500 real query positions per t
#define SP_   (WS_*HW_)     // 2500
#define NPT_  60            // 128-wide position tiles (k4/k5)
#define QT_   (NPT_*128)    // 7680 padded positions per t (= 30 x 256 for k6)
#define KPAD_ 512
#define KROWS_ (WAY_*KPAD_) // 2560
#define C8_   (C_/8)        // 80
#define BM_   256           // k6 block rows
#define BN_   256           // k6 block cols

typedef _Float16 f16;
typedef _Float16 f16x8 __attribute__((ext_vector_type(8)));
typedef _Float16 f16x4 __attribute__((ext_vector_type(4)));
typedef _Float16 f16x16 __attribute__((ext_vector_type(16)));
typedef float    f32x4 __attribute__((ext_vector_type(4)));
typedef float    f32x16 __attribute__((ext_vector_type(16)));
typedef uint32_t u32;

// offset imm kept 0 (R7 NaN lesson); per-lane global pointers instead.
__device__ __forceinline__ void gl_lds16(const f16* g, f16* l) {
  __builtin_amdgcn_global_load_lds(
      (const __attribute__((address_space(1))) u32*)g,
      (__attribute__((address_space(3))) u32*)l, 16, 0, 0);
}

// ---------------- Kpad: zero only the true pad regions (replaces 5 memsets) -
__global__ __launch_bounds__(256) void kpad(
    f16* __restrict__ Bq_raw, f16* __restrict__ As_raw,
    float* __restrict__ rq_inv, float* __restrict__ rq_nrm) {
  int idx = blockIdx.x*256 + threadIdx.x;
  const float4 z4 = make_float4(0.f, 0.f, 0.f, 0.f);
  if (idx < T_*C8_*(QT_-QP_)) {                    // Bq_raw pad positions
    int pp = idx % (QT_-QP_); int m = idx / (QT_-QP_);
    int c8 = m % C8_; int t = m / C8_;
    *reinterpret_cast<float4*>(Bq_raw + ((size_t)(t*C8_+c8)*QT_ + QP_ + pp)*8) = z4;
    return;
  }
  int i2 = idx - T_*C8_*(QT_-QP_);
  if (i2 < T_*C8_*WAY_*12) {                       // As_raw pad rows (500..511)
    int r = i2 % 12; int m = i2 / 12;
    int wy = m % WAY_; m /= WAY_;
    int c8 = m % C8_; int t = m / C8_;
    *reinterpret_cast<float4*>(
        As_raw + ((size_t)(t*C8_+c8)*KROWS_ + (size_t)wy*KPAD_ + 500 + r)*8) = z4;
    return;
  }
  int i3 = i2 - T_*C8_*WAY_*12;
  if (i3 < T_*(QT_-QP_)) {                         // rq norm pads
    int pp = i3 % (QT_-QP_); int t = i3 / (QT_-QP_);
    rq_inv[(size_t)t*QT_ + QP_ + pp] = 0.f;
    rq_nrm[(size_t)t*QT_ + QP_ + pp] = 0.f;
  }
}

// ---------------- K0: raw-feature inverse norms (4-way c-split ILP) --------
__global__ __launch_bounds__(512) void k0_invnorm(
    const float* __restrict__ q, const float* __restrict__ s,
    float* __restrict__ rq_inv, float* __restrict__ rq_nrm,
    float* __restrict__ rs_inv, float* __restrict__ rs_nrm) {
  __shared__ float part[4][128];
  int b = blockIdx.x;
  int t = b / (WQ_ + WS_);
  int n = b % (WQ_ + WS_);
  int tid = threadIdx.x;
  int seg = tid >> 7, p = tid & 127;
  const float* base; float* oi; float* on; size_t idx;
  if (n < WQ_) {
    base = q + ((size_t)(t*WQ_ + n))*C_*HW_;
    idx = (size_t)t*QT_ + n*HW_ + p; oi = rq_inv; on = rq_nrm;
  } else {
    int m = n - WQ_;
    base = s + ((size_t)(t*WS_ + m))*C_*HW_;
    idx = (size_t)t*SP_ + m*HW_ + p; oi = rs_inv; on = rs_nrm;
  }
  float ss = 0.f;
  if (p < HW_) {
    for (int c = seg*160; c < seg*160 + 160; ++c) {
      float v = base[c*HW_ + p]; ss += v*v;
    }
  }
  part[seg][p] = ss;
  __syncthreads();
  if (seg == 0 && p < HW_) {
    float tot = part[0][p] + part[1][p] + part[2][p] + part[3][p];
    float nrm = fmaxf(sqrtf(tot), 1e-12f);
    oi[idx] = 1.f/nrm; on[idx] = nrm;
  }
}

// ---------------- Kw: pack W_conv (+ w1 transpose, f16) ----
__global__ __launch_bounds__(256) void kw_packW(
    const float* __restrict__ W, const float* __restrict__ w1,
    f16* __restrict__ Wr, f16* __restrict__ Wt8, f16* __restrict__ w1t) {
  int idx = blockIdx.x*256 + threadIdx.x;
  if (idx < C_*C8_) {
    int o = idx / C8_, c8 = idx % C8_;
    f16x8 v;
#pragma unroll
    for (int i = 0; i < 8; ++i) v[i] = (f16)W[(size_t)o*C_ + c8*8 + i];
    *reinterpret_cast<f16x8*>(Wr + (size_t)o*C_ + c8*8) = v;
    *reinterpret_cast<f16x8*>(Wt8 + ((size_t)c8*C_ + o)*8) = v;
  } else if (idx < C_*C8_ + 48*C8_) {
    int k2 = idx - C_*C8_;
    int h = k2 / C8_, c8 = k2 % C8_;
    f16x8 v;
#pragma unroll
    for (int i = 0; i < 8; ++i)
      v[i] = (h < HID_) ? (f16)w1[(size_t)(c8*8+i)*HID_ + h] : (f16)0.f;
    *reinterpret_cast<f16x8*>(w1t + (size_t)h*C_ + c8*8) = v;
  }
}

// ---------------- K1: pack query raw normalized [t][c8][QT][8] (pos-linear) -
__global__ __launch_bounds__(256) void k1_pack_qraw(
    const float* __restrict__ q, const float* __restrict__ rq_inv,
    f16* __restrict__ Bq_raw) {
  int b = blockIdx.x;               // T*WQ*10
  int ct = b % 10; b /= 10;
  int qq = b % WQ_; int t = b / WQ_;
  int c0 = ct*64;
  __shared__ float lds[64*HW_];
  const float4* s4 = reinterpret_cast<const float4*>(
      q + (((size_t)(t*WQ_ + qq))*C_ + c0)*HW_);
  float4* l4 = reinterpret_cast<float4*>(lds);
  for (int i = threadIdx.x; i < 64*HW_/4; i += 256) l4[i] = s4[i];
  __syncthreads();
  for (int ch = threadIdx.x; ch < 8*HW_; ch += 256) {
    int lc8 = ch / HW_, p = ch % HW_;
    float inv = rq_inv[(size_t)t*QT_ + qq*HW_ + p];
    f16x8 v;
#pragma unroll
    for (int i = 0; i < 8; ++i) v[i] = (f16)(lds[(lc8*8 + i)*HW_ + p] * inv);
    *reinterpret_cast<f16x8*>(
        Bq_raw + ((size_t)(t*C8_ + c0/8 + lc8)*QT_ + qq*HW_ + p)*8) = v;
  }
}

// ---------------- K2: pack support raw normalized, c8-tiled [t][c8][krow][8]
__global__ __launch_bounds__(256) void k2_pack_sraw(
    const float* __restrict__ s, const float* __restrict__ rs_inv,
    f16* __restrict__ As_raw) {
  int b = blockIdx.x;               // T*WS*10
  int ct = b % 10; b /= 10;
  int n = b % WS_; int t = b / WS_;
  int c0 = ct*64;
  __shared__ float lds[64*HW_];
  const float4* s4 = reinterpret_cast<const float4*>(
      s + (((size_t)(t*WS_ + n))*C_ + c0)*HW_);
  float4* l4 = reinterpret_cast<float4*>(lds);
  for (int i = threadIdx.x; i < 64*HW_/4; i += 256) l4[i] = s4[i];
  __syncthreads();
  for (int ch = threadIdx.x; ch < HW_*8; ch += 256) {
    int p = ch / 8, cc = ch % 8;
    float inv = rs_inv[t*SP_ + n*HW_ + p];
    f16x8 v;
#pragma unroll
    for (int i = 0; i < 8; ++i) v[i] = (f16)(lds[(cc*8 + i)*HW_ + p] * inv);
    int k = n*HW_ + p;
    int way = k / 500, ki = k % 500;
    size_t row = (size_t)way*KPAD_ + ki;
    *reinterpret_cast<f16x8*>(As_raw + ((size_t)(t*C8_ + c0/8 + cc)*KROWS_ + row)*8) = v;
  }
}

// ---------------- K3: support embed GEMM + BN + leaky + l2norm -------------
// 32-row blocks; pad rows now STORE ZERO (so As_emb needs no memset).
__global__ __launch_bounds__(512) void k3_embed_support(
    const f16* __restrict__ As_raw, const f16* __restrict__ Wt8,
    const float* __restrict__ rs_nrm,
    const float* __restrict__ g, const float* __restrict__ be,
    const float* __restrict__ mu, const float* __restrict__ va,
    f16* __restrict__ As_emb) {
  int b = blockIdx.x;
  int t = b / (KROWS_/32);
  int row0 = (b % (KROWS_/32)) * 32;
  int tid = threadIdx.x, wv = tid >> 6, lane = tid & 63;
  int mf = wv & 1, nh = wv >> 1;
  __shared__ f16 Alds[32*32];
  __shared__ f16 Blds[32*C_];
  __shared__ float rowss[32];
  f32x4 acc[10];
#pragma unroll
  for (int i = 0; i < 10; ++i) acc[i] = (f32x4){0.f,0.f,0.f,0.f};

  for (int cs = 0; cs < 20; ++cs) {
    if (tid < 128) {
      int c8l = tid >> 5, r = tid & 31;
      *reinterpret_cast<f16x8*>(Alds + (c8l*32 + r)*8) =
        *reinterpret_cast<const f16x8*>(
            As_raw + ((size_t)(t*C8_ + cs*4 + c8l)*KROWS_ + row0 + r)*8);
    }
    const f16x8* bsrc = reinterpret_cast<const f16x8*>(Wt8 + (size_t)(cs*4)*C_*8);
    f16x8* bdst = reinterpret_cast<f16x8*>(Blds);
    for (int i = tid; i < 4*C_; i += 512) bdst[i] = bsrc[i];
    __syncthreads();
    f16x8 a = *reinterpret_cast<const f16x8*>(
        Alds + ((lane>>4)*32 + mf*16 + (lane&15))*8);
#pragma unroll
    for (int nf = 0; nf < 10; ++nf) {
      int o = nh*160 + nf*16 + (lane & 15);
      f16x8 bf = *reinterpret_cast<const f16x8*>(Blds + (((lane>>4)*C_) + o)*8);
      acc[nf] = __builtin_amdgcn_mfma_f32_16x16x32_f16(a, bf, acc[nf], 0, 0, 0);
    }
    __syncthreads();
  }

  if (tid < 32) rowss[tid] = 0.f;
  __syncthreads();
  int rg = lane >> 4, cl = lane & 15;
  int lrow = mf*16 + rg*4;
  int prow = row0 + lrow;
#pragma unroll
  for (int j = 0; j < 4; ++j) {
    int pr = prow + j;
    int way = pr / KPAD_, ki = pr - way*KPAD_;
    bool valid = ki < 500;
    float nrm = valid ? rs_nrm[t*SP_ + way*500 + ki] : 0.f;
    float ssum = 0.f;
#pragma unroll
    for (int nf = 0; nf < 10; ++nf) {
      int o = nh*160 + nf*16 + cl;
      float inv = g[o] / sqrtf(va[o] + 1e-5f);
      float sh = be[o] - mu[o]*inv;
      float y = acc[nf][j]*nrm*inv + sh;
      y = (y >= 0.f) ? y : 0.2f*y;
      if (!valid) y = 0.f;
      acc[nf][j] = y;
      ssum += y*y;
    }
#pragma unroll
    for (int m = 1; m < 16; m <<= 1) ssum += __shfl_xor(ssum, m);
    if (cl == 0) atomicAdd(&rowss[lrow + j], ssum);
  }
  __syncthreads();
#pragma unroll
  for (int j = 0; j < 4; ++j) {
    int pr = prow + j;
    float invn = 1.f / fmaxf(sqrtf(rowss[lrow + j]), 1e-12f);
    // pad rows: acc == 0 -> stores 0 (no memset needed)
#pragma unroll
    for (int nf = 0; nf < 10; ++nf) {
      int o = nh*160 + nf*16 + cl;
      As_emb[((size_t)(t*C8_ + (o>>3))*KROWS_ + pr)*8 + (o&7)] = (f16)(acc[nf][j]*invn);
    }
  }
}

// ---------------- K4: query embed GEMM + BN + leaky (pos-tile version) -----
__global__ __launch_bounds__(256, 3) void k4_embed_query(
    const f16* __restrict__ Wr, const f16* __restrict__ Bq_raw,
    const float* __restrict__ rq_nrm,
    const float* __restrict__ g, const float* __restrict__ be,
    const float* __restrict__ mu, const float* __restrict__ va,
    f16* __restrict__ Bq_emb) {
  __shared__ f16 Ab[3][128*32];
  __shared__ f16 Bb[3][4*128*8];
  int b = blockIdx.x;               // (t*NPT + pt)*5 + ot
  int ot = b % 5; int m = b / 5;
  int pt = m % NPT_; int t = m / NPT_;
  int o0 = ot*128;
  int tid = threadIdx.x, w = tid >> 6, lane = tid & 63;
  int la_r = lane >> 2, la_c = lane & 3;

  auto stage = [&](int buf, int cs) {
#pragma unroll
    for (int i = 0; i < 2; ++i) {
      int ca = w*2 + i;
      int r = ca*16 + la_r;
      int sc = la_c ^ (r & 3);
      gl_lds16(Wr + (size_t)(o0 + r)*C_ + cs*32 + sc*8, &Ab[buf][ca*512]);
    }
#pragma unroll
    for (int i = 0; i < 2; ++i) {
      int cb = w*2 + i;
      int c8l = cb >> 1;
      size_t src = ((size_t)(t*C8_ + cs*4 + c8l)*QT_ + pt*128 + (cb&1)*64 + lane)*8;
      gl_lds16(Bq_raw + src, &Bb[buf][(c8l*128 + (cb&1)*64)*8]);
    }
  };

  f32x4 acc[2][8];
#pragma unroll
  for (int a = 0; a < 2; ++a)
#pragma unroll
    for (int n = 0; n < 8; ++n) acc[a][n] = (f32x4){0.f,0.f,0.f,0.f};

  stage(0, 0);
  stage(1, 1);
  for (int cs = 0; cs < 20; ++cs) {
    int buf = cs % 3;
    if (cs < 19) asm volatile("s_waitcnt vmcnt(4)" ::: "memory");
    else         asm volatile("s_waitcnt vmcnt(0)" ::: "memory");
    __builtin_amdgcn_s_barrier();
    if (cs < 18) stage((cs+2)%3, cs+2);
    __builtin_amdgcn_s_setprio(1);
    f16x8 fa[2];
#pragma unroll
    for (int mi = 0; mi < 2; ++mi) {
      int R = w*32 + mi*16 + (lane & 15);
      int sc = (lane >> 4) ^ (R & 3);
      fa[mi] = *reinterpret_cast<const f16x8*>(&Ab[buf][R*32 + sc*8]);
    }
#pragma unroll
    for (int nf = 0; nf < 8; ++nf) {
      f16x8 fb = *reinterpret_cast<const f16x8*>(
          &Bb[buf][((lane>>4)*128 + nf*16 + (lane&15))*8]);
#pragma unroll
      for (int mi = 0; mi < 2; ++mi)
        acc[mi][nf] = __builtin_amdgcn_mfma_f32_16x16x32_f16(fa[mi], fb, acc[mi][nf], 0, 0, 0);
    }
    __builtin_amdgcn_s_setprio(0);
  }

#pragma unroll
  for (int mi = 0; mi < 2; ++mi) {
    int obase = o0 + w*32 + mi*16 + (lane>>4)*4;
    float inv4[4], sh4[4];
#pragma unroll
    for (int j = 0; j < 4; ++j) {
      int o = obase + j;
      inv4[j] = g[o] / sqrtf(va[o] + 1e-5f);
      sh4[j] = be[o] - mu[o]*inv4[j];
    }
#pragma unroll
    for (int nf = 0; nf < 8; ++nf) {
      size_t gp = (size_t)pt*128 + nf*16 + (lane & 15);
      float nrmv = rq_nrm[(size_t)t*QT_ + gp];
      f16x4 vv;
#pragma unroll
      for (int j = 0; j < 4; ++j) {
        float y = (nrmv > 0.f) ? (acc[mi][nf][j]*nrmv*inv4[j] + sh4[j]) : 0.f;
        y = (y >= 0.f) ? y : 0.2f*y;
        vv[j] = (f16)y;
      }
      *reinterpret_cast<f16x4*>(
          &Bq_emb[((size_t)(t*C8_ + (obase>>3))*QT_ + gp)*8 + (obase&7)]) = vv;
    }
  }
}

// ---------------- K5: column l2norm scalars + psi MLP -> cv, invq ----------
__global__ __launch_bounds__(256) void k5_colnorm_psi(
    const f16* __restrict__ Bq_emb, const f16* __restrict__ w1t,
    const float* __restrict__ b1, const float* __restrict__ w2,
    const float* __restrict__ b2, float* __restrict__ cv,
    float* __restrict__ invq) {
  __shared__ float ssA[2][128];
  __shared__ float invs[128];
  __shared__ float hidL[48*128];
  int bq = blockIdx.x;              // t*NPT + pt
  int pt = bq % NPT_, t = bq / NPT_;
  int tid = threadIdx.x, w = tid >> 6, lane = tid & 63;
  size_t pbase = (size_t)pt*128;

  auto bptr = [&](int c8, int pp) -> const f16* {
    return Bq_emb + ((size_t)(t*C8_ + c8)*QT_ + pbase + pp)*8;
  };

  {
    int h2 = tid >> 7, pp = tid & 127;
    float ss = 0.f;
    for (int c8 = h2*40; c8 < h2*40 + 40; ++c8) {
      f16x8 v = *reinterpret_cast<const f16x8*>(bptr(c8, pp));
#pragma unroll
      for (int i = 0; i < 8; ++i) { float x = (float)v[i]; ss += x*x; }
    }
    ssA[h2][pp] = ss;
  }
  for (int i = tid; i < 48*128; i += 256) hidL[i] = 0.f;
  __syncthreads();
  if (tid < 128) {
    float ss = ssA[0][tid] + ssA[1][tid];
    float inv = (ss > 0.f) ? (1.f / fmaxf(sqrtf(ss), 1e-12f)) : 0.f;
    invs[tid] = inv;
    invq[(size_t)t*QT_ + pbase + tid] = inv;
  }

  f32x4 acc[3][8];
#pragma unroll
  for (int a = 0; a < 3; ++a)
#pragma unroll
    for (int n = 0; n < 8; ++n) acc[a][n] = (f32x4){0.f,0.f,0.f,0.f};
  for (int r = 0; r < 5; ++r) {
    int cs = w + r*4;
    f16x8 fa[3];
#pragma unroll
    for (int mf = 0; mf < 3; ++mf) {
      int R = mf*16 + (lane & 15);
      fa[mf] = *reinterpret_cast<const f16x8*>(&w1t[(size_t)R*C_ + cs*32 + (lane>>4)*8]);
    }
#pragma unroll
    for (int nf = 0; nf < 8; ++nf) {
      f16x8 fb = *reinterpret_cast<const f16x8*>(
          bptr(cs*4 + (lane>>4), nf*16 + (lane&15)));
#pragma unroll
      for (int mf = 0; mf < 3; ++mf)
        acc[mf][nf] = __builtin_amdgcn_mfma_f32_16x16x32_f16(fa[mf], fb, acc[mf][nf], 0, 0, 0);
    }
  }
  __syncthreads();
  for (int rr = 0; rr < 4; ++rr) {
    if (w == rr) {
#pragma unroll
      for (int mf = 0; mf < 3; ++mf)
#pragma unroll
        for (int nf = 0; nf < 8; ++nf)
#pragma unroll
          for (int j = 0; j < 4; ++j) {
            int row = mf*16 + (lane>>4)*4 + j;
            int col = nf*16 + (lane & 15);
            hidL[row*128 + col] += acc[mf][nf][j];
          }
    }
    __syncthreads();
  }
  if (tid < 128) {
    float inv = invs[tid];
    float z = b2[0];
    for (int h = 0; h < HID_; ++h) {
      float hv = hidL[h*128 + tid]*inv + b1[h];
      hv = (hv >= 0.f) ? hv : 0.2f*hv;
      z += hv*w2[h];
    }
    cv[(size_t)t*QT_ + pbase + tid] = 0.3f/(1.f + __expf(-z)) + 0.5f;
  }
}

// ---------------- K6: fused dual cosine GEMM + gate + k-reduce --------------
// 512 threads, 256 rows x 256 cols per block (8 waves: 4 row-groups x 2
// col-halves, 64x128 per wave). 3-buf, vmcnt(4), 40 phases. LDS 100 KB.
__global__ __launch_bounds__(512, 1) void k6_main(
    const f16* __restrict__ As_emb, const f16* __restrict__ As_raw,
    const f16* __restrict__ Bq_emb, const f16* __restrict__ Bq_raw,
    const float* __restrict__ cv, const float* __restrict__ invq,
    float* __restrict__ Spart, float* __restrict__ L1part) {
  __shared__ f16 Ab[3][4*BM_*8];       // [buf][c8l][row(256)][8] = 16 KB each
  __shared__ f16 Bb[3][4*BN_*8];       // [buf][c8l][col(256)][8] = 16 KB each
  __shared__ float cvs[BN_], iqs[BN_], Ss[BN_], L1s[BN_];

  // bijective XCD map: 600 = 8*75; (way,kt) innermost for B-tile L2 reuse
  int bid = blockIdx.x;
  int l = (bid & 7)*75 + (bid >> 3);
  int wk = l % 10; int m = l / 10;     // m in [0,60)
  int pt = m % 30; int t = m / 30;
  int way = wk >> 1, kt = wk & 1;

  int tid = threadIdx.x, w = tid >> 6, lane = tid & 63;
  if (tid < BN_) {
    cvs[tid] = cv[(size_t)t*QT_ + pt*256 + tid];
    iqs[tid] = invq[(size_t)t*QT_ + pt*256 + tid];
    Ss[tid] = 0.f; L1s[tid] = 0.f;
  }
  int wr0 = (w & 3)*64;                // wave row base
  int wc0 = (w >> 2)*128;              // wave col base
  size_t rowb = (size_t)way*KPAD_ + (size_t)kt*BM_;

  // wave w stages A chunks {2w,2w+1} (c8-plane w>>1, rows ((2w)&3)*64..+127)
  // and B chunks {2w,2w+1} analogously. 4 loads/wave/stage.
  const size_t aoff = ((size_t)(t*C8_ + (w>>1))*KROWS_ + rowb + ((2*w)&3)*64 + lane)*8;
  const size_t boff = ((size_t)(t*C8_ + (w>>1))*QT_ + (size_t)pt*256 + ((2*w)&3)*64 + lane)*8;
  const f16* pA = As_raw + aoff;       // RAW pass first
  const f16* pB = Bq_raw + boff;
  const f16* pA1 = As_emb + aoff;
  const f16* pB1 = Bq_emb + boff;
  const int CS_A = 4*KROWS_*8;
  const int CS_B = 4*QT_*8;

  auto stage = [&](int buf, const f16* a, const f16* bsrc) {
    gl_lds16(a,       &Ab[buf][(2*w)*512]);
    gl_lds16(a + 512, &Ab[buf][(2*w)*512 + 512]);
    gl_lds16(bsrc,       &Bb[buf][(2*w)*512]);
    gl_lds16(bsrc + 512, &Bb[buf][(2*w)*512 + 512]);
  };

  f32x16 acc[2][4];
  f16x16 mtc[2][4];
#pragma unroll
  for (int mi = 0; mi < 2; ++mi)
#pragma unroll
    for (int nf = 0; nf < 4; ++nf) acc[mi][nf] = (f32x16)(0.f);
  float Sl[4] = {0,0,0,0}, L1l[4] = {0,0,0,0};

  stage(0, pA, pB); pA += CS_A; pB += CS_B;
  stage(1, pA, pB); pA += CS_A; pB += CS_B;

  for (int ph = 0; ph < 40; ++ph) {
    if (ph == 18) { pA = pA1; pB = pB1; }
    int buf = ph % 3;
    if (ph < 39) asm volatile("s_waitcnt vmcnt(4)" ::: "memory");
    else         asm volatile("s_waitcnt vmcnt(0)" ::: "memory");
    __builtin_amdgcn_s_barrier();
    if (ph < 38) { stage((ph+2)%3, pA, pB); pA += CS_A; pB += CS_B; }
    __builtin_amdgcn_s_setprio(1);
    const f16* Abuf = Ab[buf];
    const f16* Bbuf = Bb[buf];
    int r0 = wr0 + (lane & 31);
#pragma unroll
    for (int ks = 0; ks < 2; ++ks) {
      int c8l = ks*2 + (lane >> 5);
      f16x8 fa0 = *reinterpret_cast<const f16x8*>(&Abuf[(c8l*BM_ + r0)*8]);
      f16x8 fa1 = *reinterpret_cast<const f16x8*>(&Abuf[(c8l*BM_ + r0 + 32)*8]);
#pragma unroll
      for (int nf = 0; nf < 4; ++nf) {
        f16x8 fb = *reinterpret_cast<const f16x8*>(
            &Bbuf[(c8l*BN_ + wc0 + nf*32 + (lane & 31))*8]);
        acc[0][nf] = __builtin_amdgcn_mfma_f32_32x32x16_f16(fa0, fb, acc[0][nf], 0, 0, 0);
        acc[1][nf] = __builtin_amdgcn_mfma_f32_32x32x16_f16(fa1, fb, acc[1][nf], 0, 0, 0);
      }
    }
    __builtin_amdgcn_s_setprio(0);

    if (ph == 19) {
#pragma unroll
      for (int mi = 0; mi < 2; ++mi)
#pragma unroll
        for (int nf = 0; nf < 4; ++nf)
#pragma unroll
          for (int jj = 0; jj < 16; ++jj) {
            mtc[mi][nf][jj] = (f16)fminf(fmaxf(acc[mi][nf][jj], -8.f), 8.f);
            acc[mi][nf][jj] = 0.f;
          }
    } else if (ph == 39) {
#pragma unroll
      for (int nf = 0; nf < 4; ++nf) {
        int col = wc0 + nf*32 + (lane & 31);
        float cvv = cvs[col];
        float iq = iqs[col];
#pragma unroll
        for (int mi = 0; mi < 2; ++mi)
#pragma unroll
          for (int jj = 0; jj < 16; ++jj) {
            float fx = acc[mi][nf][jj] * iq;
            float sg = 1.f/(1.f + __expf(-50.f*(fx - cvv)));
            Sl[nf]  += sg * (float)mtc[mi][nf][jj];
            L1l[nf] += sg;
          }
      }
    }
  }

#pragma unroll
  for (int nf = 0; nf < 4; ++nf) {
    float vs = Sl[nf] + __shfl_xor(Sl[nf], 32);
    float vl = L1l[nf] + __shfl_xor(L1l[nf], 32);
    if (lane < 32) {
      atomicAdd(&Ss[wc0 + nf*32 + lane], vs);
      atomicAdd(&L1s[wc0 + nf*32 + lane], vl);
    }
  }
  __syncthreads();
  if (tid < BN_) {
    size_t o = ((size_t)((t*WAY_ + way)*2 + kt))*QT_ + (size_t)pt*256 + tid;
    Spart[o] = Ss[tid]; L1part[o] = L1s[tid];
  }
}

// ---------------- K7: final score reduce -----------------------------------
__global__ __launch_bounds__(128) void k7_reduce(
    const float* __restrict__ Spart, const float* __restrict__ L1part,
    float* __restrict__ out) {
  int b = blockIdx.x;               // t*WQ+q
  int t = b / WQ_, q = b % WQ_;
  int tid = threadIdx.x;
  __shared__ float red[128];
  float contrib[WAY_] = {0,0,0,0,0};
  if (tid < HW_) {
    size_t p = (size_t)q*HW_ + tid;
    float l1 = 0.f;
#pragma unroll
    for (int w = 0; w < WAY_; ++w)
#pragma unroll
      for (int k = 0; k < 2; ++k)
        l1 += L1part[((size_t)((t*WAY_ + w)*2 + k))*QT_ + p];
    l1 = fmaxf(l1, 1e-12f);
#pragma unroll
    for (int w = 0; w < WAY_; ++w) {
      float sv = 0.f;
#pragma unroll
      for (int k = 0; k < 2; ++k)
        sv += Spart[((size_t)((t*WAY_ + w)*2 + k))*QT_ + p];
      contrib[w] = sv / l1;
    }
  }
#pragma unroll
  for (int w = 0; w < WAY_; ++w) {
    red[tid] = contrib[w];
    __syncthreads();
    for (int off = 64; off > 0; off >>= 1) {
      if (tid < off) red[tid] += red[tid + off];
      __syncthreads();
    }
    if (tid == 0) out[b*WAY_ + w] = red[0] * 30.f / (float)(HW_*5);
    __syncthreads();
  }
}

// ---------------- launch ----------------------------------------------------
extern "C" void kernel_launch(void* const* d_in, const int* in_sizes, int n_in,
                              void* d_out, int out_size, void* d_ws, size_t ws_size,
                              hipStream_t stream) {
  (void)in_sizes; (void)n_in; (void)out_size; (void)ws_size;
  const float* q  = (const float*)d_in[0];
  const float* s  = (const float*)d_in[1];
  const float* W  = (const float*)d_in[2];
  const float* g  = (const float*)d_in[3];
  const float* be = (const float*)d_in[4];
  const float* mu = (const float*)d_in[5];
  const float* va = (const float*)d_in[6];
  const float* w1 = (const float*)d_in[7];
  const float* b1 = (const float*)d_in[8];
  const float* w2 = (const float*)d_in[9];
  const float* b2 = (const float*)d_in[10];
  float* out = (float*)d_out;
  char* ws = (char*)d_ws;

  size_t off = 0;
  auto nxt = [&](size_t bytes) { size_t o = off; off += (bytes + 255) & ~(size_t)255; return o; };
  float* rq_inv = (float*)(ws + nxt((size_t)T_*QT_*4));
  float* rq_nrm = (float*)(ws + nxt((size_t)T_*QT_*4));
  float* rs_inv = (float*)(ws + nxt((size_t)T_*SP_*4));
  float* rs_nrm = (float*)(ws + nxt((size_t)T_*SP_*4));
  f16* Wr     = (f16*)(ws + nxt((size_t)C_*C_*2));
  f16* Wt8    = (f16*)(ws + nxt((size_t)C_*C_*2));
  f16* w1t    = (f16*)(ws + nxt((size_t)48*C_*2));
  f16* As_raw = (f16*)(ws + nxt((size_t)T_*KROWS_*C_*2));
  f16* As_emb = (f16*)(ws + nxt((size_t)T_*KROWS_*C_*2));
  f16* Bq_raw = (f16*)(ws + nxt((size_t)T_*C8_*QT_*8*2));
  f16* Bq_emb = (f16*)(ws + nxt((size_t)T_*C8_*QT_*8*2));
  float* cvp    = (float*)(ws + nxt((size_t)T_*QT_*4));
  float* invq   = (float*)(ws + nxt((size_t)T_*QT_*4));
  float* Spart  = (float*)(ws + nxt((size_t)T_*WAY_*2*QT_*4));
  float* L1part = (float*)(ws + nxt((size_t)T_*WAY_*2*QT_*4));

  int padN = T_*C8_*(QT_-QP_) + T_*C8_*WAY_*12 + T_*(QT_-QP_);
  kpad<<<(padN + 255)/256, 256, 0, stream>>>(Bq_raw, As_raw, rq_inv, rq_nrm);
  k0_invnorm<<<T_*(WQ_+WS_), 512, 0, stream>>>(q, s, rq_inv, rq_nrm, rs_inv, rs_nrm);
  kw_packW<<<(C_*C8_ + 48*C8_ + 255)/256, 256, 0, stream>>>(W, w1, Wr, Wt8, w1t);
  k1_pack_qraw<<<T_*WQ_*10, 256, 0, stream>>>(q, rq_inv, Bq_raw);
  k2_pack_sraw<<<T_*WS_*10, 256, 0, stream>>>(s, rs_inv, As_raw);
  k3_embed_support<<<T_*(KROWS_/32), 512, 0, stream>>>(As_raw, Wt8, rs_nrm, g, be, mu, va, As_emb);
  k4_embed_query<<<T_*5*NPT_, 256, 0, stream>>>(Wr, Bq_raw, rq_nrm, g, be, mu, va, Bq_emb);
  k5_colnorm_psi<<<T_*NPT_, 256, 0, stream>>>(Bq_emb, w1t, b1, w2, b2, cvp, invq);
  k6_main<<<600, 512, 0, stream>>>(As_emb, As_raw, Bq_emb, Bq_raw, cvp, invq, Spart, L1part);
  k7_reduce<<<T_*WQ_, 128, 0, stream>>>(Spart, L1part, out);
}

// Round 13
// 283.688 us; speedup vs baseline: 1.1104x; 1.1104x over previous
//
#include <hip/hip_runtime.h>
#include <stdint.h>

// ---------------- problem constants ----------------
#define T_    2
#define WQ_   75
#define WS_   25
#define C_    640
#define HW_   100
#define HID_  40
#define WAY_  5
#define QP_   (WQ_*HW_)     // 7500 real query positions per t
#define SP_   (WS_*HW_)     // 2500
#define NPT_  60            // 128-wide position tiles
#define QT_   (NPT_*128)    // 7680 padded positions per t
#define KPAD_ 512
#define KROWS_ (WAY_*KPAD_) // 2560
#define C8_   (C_/8)        // 80
#define BM_   256           // k6 block rows
#define BNK_  128           // k6 block cols

typedef _Float16 f16;
typedef _Float16 f16x8 __attribute__((ext_vector_type(8)));
typedef _Float16 f16x4 __attribute__((ext_vector_type(4)));
typedef _Float16 f16x16 __attribute__((ext_vector_type(16)));
typedef float    f32x4 __attribute__((ext_vector_type(4)));
typedef float    f32x16 __attribute__((ext_vector_type(16)));
typedef uint32_t u32;

// offset imm kept 0 (R7 NaN lesson); per-lane global pointers instead.
__device__ __forceinline__ void gl_lds16(const f16* g, f16* l) {
  __builtin_amdgcn_global_load_lds(
      (const __attribute__((address_space(1))) u32*)g,
      (__attribute__((address_space(3))) u32*)l, 16, 0, 0);
}

// ---------------- Ksetup: k0 norms + W packs + pad zeroing (merged) --------
#define NB0_ (T_*(WQ_+WS_))                       // 200 norm blocks
#define KWN_ (C_*C8_ + 48*C8_)                    // 55040 pack elems
#define NBW_ ((KWN_ + 511)/512)                   // 108
#define PADN_ (T_*C8_*(QT_-QP_) + T_*C8_*WAY_*12 + T_*(QT_-QP_))  // 38760
#define NBP_ ((PADN_ + 511)/512)                  // 76

__global__ __launch_bounds__(512) void ksetup(
    const float* __restrict__ q, const float* __restrict__ s,
    const float* __restrict__ W, const float* __restrict__ w1,
    float* __restrict__ rq_inv, float* __restrict__ rq_nrm,
    float* __restrict__ rs_inv, float* __restrict__ rs_nrm,
    f16* __restrict__ Wr, f16* __restrict__ Wt8, f16* __restrict__ w1t,
    f16* __restrict__ Bq_raw, f16* __restrict__ As_raw) {
  int blk = blockIdx.x;
  int tid = threadIdx.x;

  if (blk < NB0_) {
    // ---- part 1: raw-feature inverse norms (4-way c-split) ----
    __shared__ float part[4][128];
    int t = blk / (WQ_ + WS_);
    int n = blk % (WQ_ + WS_);
    int seg = tid >> 7, p = tid & 127;
    const float* base; float* oi; float* on; size_t idx;
    if (n < WQ_) {
      base = q + ((size_t)(t*WQ_ + n))*C_*HW_;
      idx = (size_t)t*QT_ + n*HW_ + p; oi = rq_inv; on = rq_nrm;
    } else {
      int m = n - WQ_;
      base = s + ((size_t)(t*WS_ + m))*C_*HW_;
      idx = (size_t)t*SP_ + m*HW_ + p; oi = rs_inv; on = rs_nrm;
    }
    float ss = 0.f;
    if (p < HW_) {
      for (int c = seg*160; c < seg*160 + 160; ++c) {
        float v = base[c*HW_ + p]; ss += v*v;
      }
    }
    part[seg][p] = ss;
    __syncthreads();
    if (seg == 0 && p < HW_) {
      float tot = part[0][p] + part[1][p] + part[2][p] + part[3][p];
      float nrm = fmaxf(sqrtf(tot), 1e-12f);
      oi[idx] = 1.f/nrm; on[idx] = nrm;
    }
    return;
  }
  if (blk < NB0_ + NBW_) {
    // ---- part 2: pack W_conv (+ w1 transpose) ----
    int idx = (blk - NB0_)*512 + tid;
    if (idx < C_*C8_) {
      int o = idx / C8_, c8 = idx % C8_;
      f16x8 v;
#pragma unroll
      for (int i = 0; i < 8; ++i) v[i] = (f16)W[(size_t)o*C_ + c8*8 + i];
      *reinterpret_cast<f16x8*>(Wr + (size_t)o*C_ + c8*8) = v;
      *reinterpret_cast<f16x8*>(Wt8 + ((size_t)c8*C_ + o)*8) = v;
    } else if (idx < KWN_) {
      int k2 = idx - C_*C8_;
      int h = k2 / C8_, c8 = k2 % C8_;
      f16x8 v;
#pragma unroll
      for (int i = 0; i < 8; ++i)
        v[i] = (h < HID_) ? (f16)w1[(size_t)(c8*8+i)*HID_ + h] : (f16)0.f;
      *reinterpret_cast<f16x8*>(w1t + (size_t)h*C_ + c8*8) = v;
    }
    return;
  }
  // ---- part 3: zero true pad regions ----
  {
    int idx = (blk - NB0_ - NBW_)*512 + tid;
    const float4 z4 = make_float4(0.f, 0.f, 0.f, 0.f);
    if (idx < T_*C8_*(QT_-QP_)) {                  // Bq_raw pad positions
      int pp = idx % (QT_-QP_); int m = idx / (QT_-QP_);
      int c8 = m % C8_; int t = m / C8_;
      *reinterpret_cast<float4*>(Bq_raw + ((size_t)(t*C8_+c8)*QT_ + QP_ + pp)*8) = z4;
      return;
    }
    int i2 = idx - T_*C8_*(QT_-QP_);
    if (i2 < T_*C8_*WAY_*12) {                     // As_raw pad rows (500..511)
      int r = i2 % 12; int m = i2 / 12;
      int wy = m % WAY_; m /= WAY_;
      int c8 = m % C8_; int t = m / C8_;
      *reinterpret_cast<float4*>(
          As_raw + ((size_t)(t*C8_+c8)*KROWS_ + (size_t)wy*KPAD_ + 500 + r)*8) = z4;
      return;
    }
    int i3 = i2 - T_*C8_*WAY_*12;
    if (i3 < T_*(QT_-QP_)) {                       // rq norm pads
      int pp = i3 % (QT_-QP_); int t = i3 / (QT_-QP_);
      rq_inv[(size_t)t*QT_ + QP_ + pp] = 0.f;
      rq_nrm[(size_t)t*QT_ + QP_ + pp] = 0.f;
    }
  }
}

// ---------------- K1: pack query raw normalized [t][c8][QT][8] (pos-linear) -
__global__ __launch_bounds__(256) void k1_pack_qraw(
    const float* __restrict__ q, const float* __restrict__ rq_inv,
    f16* __restrict__ Bq_raw) {
  int b = blockIdx.x;               // T*WQ*10
  int ct = b % 10; b /= 10;
  int qq = b % WQ_; int t = b / WQ_;
  int c0 = ct*64;
  __shared__ float lds[64*HW_];
  const float4* s4 = reinterpret_cast<const float4*>(
      q + (((size_t)(t*WQ_ + qq))*C_ + c0)*HW_);
  float4* l4 = reinterpret_cast<float4*>(lds);
  for (int i = threadIdx.x; i < 64*HW_/4; i += 256) l4[i] = s4[i];
  __syncthreads();
  for (int ch = threadIdx.x; ch < 8*HW_; ch += 256) {
    int lc8 = ch / HW_, p = ch % HW_;
    float inv = rq_inv[(size_t)t*QT_ + qq*HW_ + p];
    f16x8 v;
#pragma unroll
    for (int i = 0; i < 8; ++i) v[i] = (f16)(lds[(lc8*8 + i)*HW_ + p] * inv);
    *reinterpret_cast<f16x8*>(
        Bq_raw + ((size_t)(t*C8_ + c0/8 + lc8)*QT_ + qq*HW_ + p)*8) = v;
  }
}

// ---------------- K2: pack support raw normalized, c8-tiled [t][c8][krow][8]
__global__ __launch_bounds__(256) void k2_pack_sraw(
    const float* __restrict__ s, const float* __restrict__ rs_inv,
    f16* __restrict__ As_raw) {
  int b = blockIdx.x;               // T*WS*10
  int ct = b % 10; b /= 10;
  int n = b % WS_; int t = b / WS_;
  int c0 = ct*64;
  __shared__ float lds[64*HW_];
  const float4* s4 = reinterpret_cast<const float4*>(
      s + (((size_t)(t*WS_ + n))*C_ + c0)*HW_);
  float4* l4 = reinterpret_cast<float4*>(lds);
  for (int i = threadIdx.x; i < 64*HW_/4; i += 256) l4[i] = s4[i];
  __syncthreads();
  for (int ch = threadIdx.x; ch < HW_*8; ch += 256) {
    int p = ch / 8, cc = ch % 8;
    float inv = rs_inv[t*SP_ + n*HW_ + p];
    f16x8 v;
#pragma unroll
    for (int i = 0; i < 8; ++i) v[i] = (f16)(lds[(cc*8 + i)*HW_ + p] * inv);
    int k = n*HW_ + p;
    int way = k / 500, ki = k % 500;
    size_t row = (size_t)way*KPAD_ + ki;
    *reinterpret_cast<f16x8*>(As_raw + ((size_t)(t*C8_ + c0/8 + cc)*KROWS_ + row)*8) = v;
  }
}

// ---------------- K3: support embed GEMM + BN + leaky + l2norm -------------
__global__ __launch_bounds__(512) void k3_embed_support(
    const f16* __restrict__ As_raw, const f16* __restrict__ Wt8,
    const float* __restrict__ rs_nrm,
    const float* __restrict__ g, const float* __restrict__ be,
    const float* __restrict__ mu, const float* __restrict__ va,
    f16* __restrict__ As_emb) {
  int b = blockIdx.x;
  int t = b / (KROWS_/32);
  int row0 = (b % (KROWS_/32)) * 32;
  int tid = threadIdx.x, wv = tid >> 6, lane = tid & 63;
  int mf = wv & 1, nh = wv >> 1;
  __shared__ f16 Alds[32*32];
  __shared__ f16 Blds[32*C_];
  __shared__ float rowss[32];
  f32x4 acc[10];
#pragma unroll
  for (int i = 0; i < 10; ++i) acc[i] = (f32x4){0.f,0.f,0.f,0.f};

  for (int cs = 0; cs < 20; ++cs) {
    if (tid < 128) {
      int c8l = tid >> 5, r = tid & 31;
      *reinterpret_cast<f16x8*>(Alds + (c8l*32 + r)*8) =
        *reinterpret_cast<const f16x8*>(
            As_raw + ((size_t)(t*C8_ + cs*4 + c8l)*KROWS_ + row0 + r)*8);
    }
    const f16x8* bsrc = reinterpret_cast<const f16x8*>(Wt8 + (size_t)(cs*4)*C_*8);
    f16x8* bdst = reinterpret_cast<f16x8*>(Blds);
    for (int i = tid; i < 4*C_; i += 512) bdst[i] = bsrc[i];
    __syncthreads();
    f16x8 a = *reinterpret_cast<const f16x8*>(
        Alds + ((lane>>4)*32 + mf*16 + (lane&15))*8);
#pragma unroll
    for (int nf = 0; nf < 10; ++nf) {
      int o = nh*160 + nf*16 + (lane & 15);
      f16x8 bf = *reinterpret_cast<const f16x8*>(Blds + (((lane>>4)*C_) + o)*8);
      acc[nf] = __builtin_amdgcn_mfma_f32_16x16x32_f16(a, bf, acc[nf], 0, 0, 0);
    }
    __syncthreads();
  }

  if (tid < 32) rowss[tid] = 0.f;
  __syncthreads();
  int rg = lane >> 4, cl = lane & 15;
  int lrow = mf*16 + rg*4;
  int prow = row0 + lrow;
#pragma unroll
  for (int j = 0; j < 4; ++j) {
    int pr = prow + j;
    int way = pr / KPAD_, ki = pr - way*KPAD_;
    bool valid = ki < 500;
    float nrm = valid ? rs_nrm[t*SP_ + way*500 + ki] : 0.f;
    float ssum = 0.f;
#pragma unroll
    for (int nf = 0; nf < 10; ++nf) {
      int o = nh*160 + nf*16 + cl;
      float inv = g[o] / sqrtf(va[o] + 1e-5f);
      float sh = be[o] - mu[o]*inv;
      float y = acc[nf][j]*nrm*inv + sh;
      y = (y >= 0.f) ? y : 0.2f*y;
      if (!valid) y = 0.f;
      acc[nf][j] = y;
      ssum += y*y;
    }
#pragma unroll
    for (int m = 1; m < 16; m <<= 1) ssum += __shfl_xor(ssum, m);
    if (cl == 0) atomicAdd(&rowss[lrow + j], ssum);
  }
  __syncthreads();
#pragma unroll
  for (int j = 0; j < 4; ++j) {
    int pr = prow + j;
    float invn = 1.f / fmaxf(sqrtf(rowss[lrow + j]), 1e-12f);
    // pad rows: acc == 0 -> stores 0 (no memset needed)
#pragma unroll
    for (int nf = 0; nf < 10; ++nf) {
      int o = nh*160 + nf*16 + cl;
      As_emb[((size_t)(t*C8_ + (o>>3))*KROWS_ + pr)*8 + (o&7)] = (f16)(acc[nf][j]*invn);
    }
  }
}

// ---------------- K4: query embed GEMM + BN + leaky (pos-tile version) -----
__global__ __launch_bounds__(256, 3) void k4_embed_query(
    const f16* __restrict__ Wr, const f16* __restrict__ Bq_raw,
    const float* __restrict__ rq_nrm,
    const float* __restrict__ g, const float* __restrict__ be,
    const float* __restrict__ mu, const float* __restrict__ va,
    f16* __restrict__ Bq_emb) {
  __shared__ f16 Ab[3][128*32];
  __shared__ f16 Bb[3][4*128*8];
  int b = blockIdx.x;               // (t*NPT + pt)*5 + ot
  int ot = b % 5; int m = b / 5;
  int pt = m % NPT_; int t = m / NPT_;
  int o0 = ot*128;
  int tid = threadIdx.x, w = tid >> 6, lane = tid & 63;
  int la_r = lane >> 2, la_c = lane & 3;

  auto stage = [&](int buf, int cs) {
#pragma unroll
    for (int i = 0; i < 2; ++i) {
      int ca = w*2 + i;
      int r = ca*16 + la_r;
      int sc = la_c ^ (r & 3);
      gl_lds16(Wr + (size_t)(o0 + r)*C_ + cs*32 + sc*8, &Ab[buf][ca*512]);
    }
#pragma unroll
    for (int i = 0; i < 2; ++i) {
      int cb = w*2 + i;
      int c8l = cb >> 1;
      size_t src = ((size_t)(t*C8_ + cs*4 + c8l)*QT_ + pt*128 + (cb&1)*64 + lane)*8;
      gl_lds16(Bq_raw + src, &Bb[buf][(c8l*128 + (cb&1)*64)*8]);
    }
  };

  f32x4 acc[2][8];
#pragma unroll
  for (int a = 0; a < 2; ++a)
#pragma unroll
    for (int n = 0; n < 8; ++n) acc[a][n] = (f32x4){0.f,0.f,0.f,0.f};

  stage(0, 0);
  stage(1, 1);
  for (int cs = 0; cs < 20; ++cs) {
    int buf = cs % 3;
    if (cs < 19) asm volatile("s_waitcnt vmcnt(4)" ::: "memory");
    else         asm volatile("s_waitcnt vmcnt(0)" ::: "memory");
    __builtin_amdgcn_s_barrier();
    if (cs < 18) stage((cs+2)%3, cs+2);
    __builtin_amdgcn_s_setprio(1);
    f16x8 fa[2];
#pragma unroll
    for (int mi = 0; mi < 2; ++mi) {
      int R = w*32 + mi*16 + (lane & 15);
      int sc = (lane >> 4) ^ (R & 3);
      fa[mi] = *reinterpret_cast<const f16x8*>(&Ab[buf][R*32 + sc*8]);
    }
#pragma unroll
    for (int nf = 0; nf < 8; ++nf) {
      f16x8 fb = *reinterpret_cast<const f16x8*>(
          &Bb[buf][((lane>>4)*128 + nf*16 + (lane&15))*8]);
#pragma unroll
      for (int mi = 0; mi < 2; ++mi)
        acc[mi][nf] = __builtin_amdgcn_mfma_f32_16x16x32_f16(fa[mi], fb, acc[mi][nf], 0, 0, 0);
    }
    __builtin_amdgcn_s_setprio(0);
  }

#pragma unroll
  for (int mi = 0; mi < 2; ++mi) {
    int obase = o0 + w*32 + mi*16 + (lane>>4)*4;
    float inv4[4], sh4[4];
#pragma unroll
    for (int j = 0; j < 4; ++j) {
      int o = obase + j;
      inv4[j] = g[o] / sqrtf(va[o] + 1e-5f);
      sh4[j] = be[o] - mu[o]*inv4[j];
    }
#pragma unroll
    for (int nf = 0; nf < 8; ++nf) {
      size_t gp = (size_t)pt*128 + nf*16 + (lane & 15);
      float nrmv = rq_nrm[(size_t)t*QT_ + gp];
      f16x4 vv;
#pragma unroll
      for (int j = 0; j < 4; ++j) {
        float y = (nrmv > 0.f) ? (acc[mi][nf][j]*nrmv*inv4[j] + sh4[j]) : 0.f;
        y = (y >= 0.f) ? y : 0.2f*y;
        vv[j] = (f16)y;
      }
      *reinterpret_cast<f16x4*>(
          &Bq_emb[((size_t)(t*C8_ + (obase>>3))*QT_ + gp)*8 + (obase&7)]) = vv;
    }
  }
}

// ---------------- K5: column l2norm scalars + psi MLP -> cv, invq ----------
__global__ __launch_bounds__(256) void k5_colnorm_psi(
    const f16* __restrict__ Bq_emb, const f16* __restrict__ w1t,
    const float* __restrict__ b1, const float* __restrict__ w2,
    const float* __restrict__ b2, float* __restrict__ cv,
    float* __restrict__ invq) {
  __shared__ float ssA[2][128];
  __shared__ float invs[128];
  __shared__ float hidL[48*128];
  int bq = blockIdx.x;              // t*NPT + pt
  int pt = bq % NPT_, t = bq / NPT_;
  int tid = threadIdx.x, w = tid >> 6, lane = tid & 63;
  size_t pbase = (size_t)pt*128;

  auto bptr = [&](int c8, int pp) -> const f16* {
    return Bq_emb + ((size_t)(t*C8_ + c8)*QT_ + pbase + pp)*8;
  };

  {
    int h2 = tid >> 7, pp = tid & 127;
    float ss = 0.f;
    for (int c8 = h2*40; c8 < h2*40 + 40; ++c8) {
      f16x8 v = *reinterpret_cast<const f16x8*>(bptr(c8, pp));
#pragma unroll
      for (int i = 0; i < 8; ++i) { float x = (float)v[i]; ss += x*x; }
    }
    ssA[h2][pp] = ss;
  }
  for (int i = tid; i < 48*128; i += 256) hidL[i] = 0.f;
  __syncthreads();
  if (tid < 128) {
    float ss = ssA[0][tid] + ssA[1][tid];
    float inv = (ss > 0.f) ? (1.f / fmaxf(sqrtf(ss), 1e-12f)) : 0.f;
    invs[tid] = inv;
    invq[(size_t)t*QT_ + pbase + tid] = inv;
  }

  f32x4 acc[3][8];
#pragma unroll
  for (int a = 0; a < 3; ++a)
#pragma unroll
    for (int n = 0; n < 8; ++n) acc[a][n] = (f32x4){0.f,0.f,0.f,0.f};
  for (int r = 0; r < 5; ++r) {
    int cs = w + r*4;
    f16x8 fa[3];
#pragma unroll
    for (int mf = 0; mf < 3; ++mf) {
      int R = mf*16 + (lane & 15);
      fa[mf] = *reinterpret_cast<const f16x8*>(&w1t[(size_t)R*C_ + cs*32 + (lane>>4)*8]);
    }
#pragma unroll
    for (int nf = 0; nf < 8; ++nf) {
      f16x8 fb = *reinterpret_cast<const f16x8*>(
          bptr(cs*4 + (lane>>4), nf*16 + (lane&15)));
#pragma unroll
      for (int mf = 0; mf < 3; ++mf)
        acc[mf][nf] = __builtin_amdgcn_mfma_f32_16x16x32_f16(fa[mf], fb, acc[mf][nf], 0, 0, 0);
    }
  }
  __syncthreads();
  for (int rr = 0; rr < 4; ++rr) {
    if (w == rr) {
#pragma unroll
      for (int mf = 0; mf < 3; ++mf)
#pragma unroll
        for (int nf = 0; nf < 8; ++nf)
#pragma unroll
          for (int j = 0; j < 4; ++j) {
            int row = mf*16 + (lane>>4)*4 + j;
            int col = nf*16 + (lane & 15);
            hidL[row*128 + col] += acc[mf][nf][j];
          }
    }
    __syncthreads();
  }
  if (tid < 128) {
    float inv = invs[tid];
    float z = b2[0];
    for (int h = 0; h < HID_; ++h) {
      float hv = hidL[h*128 + tid]*inv + b1[h];
      hv = (hv >= 0.f) ? hv : 0.2f*hv;
      z += hv*w2[h];
    }
    cv[(size_t)t*QT_ + pbase + tid] = 0.3f/(1.f + __expf(-z)) + 0.5f;
  }
}

// ---------------- K6: fused dual cosine GEMM + gate + k-reduce --------------
// R11-proven config: 256 thr, 4 waves x (64 rows x 128 cols), BM=256,
// 3-buf counted vmcnt(6)/dbl-prefetch, temporal RAW -> EMB, 74 KB LDS,
// 2 blocks/CU. Grid 1200 = 8 XCD x 150 exact.
__global__ __launch_bounds__(256, 2) void k6_main(
    const f16* __restrict__ As_emb, const f16* __restrict__ As_raw,
    const f16* __restrict__ Bq_emb, const f16* __restrict__ Bq_raw,
    const float* __restrict__ cv, const float* __restrict__ invq,
    float* __restrict__ Spart, float* __restrict__ L1part) {
  __shared__ f16 Ab[3][4*BM_*8];       // 16 KB each
  __shared__ f16 Bb[3][4*BNK_*8];      // 8 KB each
  __shared__ float cvs[BNK_], iqs[BNK_], Ss[BNK_], L1s[BNK_];

  // bijective XCD map: 1200 = 8*150; (way,kt) innermost for B-tile L2 reuse
  int bid = blockIdx.x;
  int l = (bid & 7)*150 + (bid >> 3);
  int wk = l % 10; int m = l / 10;     // m in [0,120)
  int pt = m % NPT_; int t = m / NPT_;
  int way = wk >> 1, kt = wk & 1;

  int tid = threadIdx.x, w = tid >> 6, lane = tid & 63;
  if (tid < BNK_) {
    cvs[tid] = cv[(size_t)t*QT_ + pt*128 + tid];
    iqs[tid] = invq[(size_t)t*QT_ + pt*128 + tid];
    Ss[tid] = 0.f; L1s[tid] = 0.f;
  }
  int wrow0 = w*64;
  size_t rowb = (size_t)way*KPAD_ + (size_t)kt*BM_;

  // wave w owns c8-plane w of both A (4 chunks) and B (2 chunks)
  const size_t aoff = ((size_t)(t*C8_ + w)*KROWS_ + rowb + lane)*8;
  const size_t boff = ((size_t)(t*C8_ + w)*QT_ + (size_t)pt*128 + lane)*8;
  const f16* pA = As_raw + aoff;       // RAW pass first
  const f16* pB = Bq_raw + boff;
  const f16* pA1 = As_emb + aoff;
  const f16* pB1 = Bq_emb + boff;
  const int CS_A = 4*KROWS_*8;
  const int CS_B = 4*QT_*8;

  auto stage = [&](int buf, const f16* a, const f16* bsrc) {
    f16* da = &Ab[buf][(size_t)w*BM_*8];
    f16* db = &Bb[buf][(size_t)w*BNK_*8];
    gl_lds16(a,        da);
    gl_lds16(a + 512,  da + 512);
    gl_lds16(a + 1024, da + 1024);
    gl_lds16(a + 1536, da + 1536);
    gl_lds16(bsrc,       db);
    gl_lds16(bsrc + 512, db + 512);
  };

  f32x16 acc[2][4];
  f16x16 mtc[2][4];
#pragma unroll
  for (int mi = 0; mi < 2; ++mi)
#pragma unroll
    for (int nf = 0; nf < 4; ++nf) acc[mi][nf] = (f32x16)(0.f);
  float Sl[4] = {0,0,0,0}, L1l[4] = {0,0,0,0};

  stage(0, pA, pB); pA += CS_A; pB += CS_B;
  stage(1, pA, pB); pA += CS_A; pB += CS_B;

  for (int ph = 0; ph < 40; ++ph) {
    if (ph == 18) { pA = pA1; pB = pB1; }
    int buf = ph % 3;
    if (ph < 39) asm volatile("s_waitcnt vmcnt(6)" ::: "memory");
    else         asm volatile("s_waitcnt vmcnt(0)" ::: "memory");
    __builtin_amdgcn_s_barrier();
    if (ph < 38) { stage((ph+2)%3, pA, pB); pA += CS_A; pB += CS_B; }
    __builtin_amdgcn_s_setprio(1);
    const f16* Abuf = Ab[buf];
    const f16* Bbuf = Bb[buf];
    int r0 = wrow0 + (lane & 31);
#pragma unroll
    for (int ks = 0; ks < 2; ++ks) {
      int c8l = ks*2 + (lane >> 5);
      f16x8 fa0 = *reinterpret_cast<const f16x8*>(&Abuf[(c8l*BM_ + r0)*8]);
      f16x8 fa1 = *reinterpret_cast<const f16x8*>(&Abuf[(c8l*BM_ + r0 + 32)*8]);
#pragma unroll
      for (int nf = 0; nf < 4; ++nf) {
        f16x8 fb = *reinterpret_cast<const f16x8*>(
            &Bbuf[(c8l*BNK_ + nf*32 + (lane & 31))*8]);
        acc[0][nf] = __builtin_amdgcn_mfma_f32_32x32x16_f16(fa0, fb, acc[0][nf], 0, 0, 0);
        acc[1][nf] = __builtin_amdgcn_mfma_f32_32x32x16_f16(fa1, fb, acc[1][nf], 0, 0, 0);
      }
    }
    __builtin_amdgcn_s_setprio(0);

    if (ph == 19) {
#pragma unroll
      for (int mi = 0; mi < 2; ++mi)
#pragma unroll
        for (int nf = 0; nf < 4; ++nf)
#pragma unroll
          for (int jj = 0; jj < 16; ++jj) {
            mtc[mi][nf][jj] = (f16)fminf(fmaxf(acc[mi][nf][jj], -8.f), 8.f);
            acc[mi][nf][jj] = 0.f;
          }
    } else if (ph == 39) {
#pragma unroll
      for (int nf = 0; nf < 4; ++nf) {
        int col = nf*32 + (lane & 31);
        float cvv = cvs[col];
        float iq = iqs[col];
#pragma unroll
        for (int mi = 0; mi < 2; ++mi)
#pragma unroll
          for (int jj = 0; jj < 16; ++jj) {
            float fx = acc[mi][nf][jj] * iq;
            float sg = 1.f/(1.f + __expf(-50.f*(fx - cvv)));
            Sl[nf]  += sg * (float)mtc[mi][nf][jj];
            L1l[nf] += sg;
          }
      }
    }
  }

#pragma unroll
  for (int nf = 0; nf < 4; ++nf) {
    float vs = Sl[nf] + __shfl_xor(Sl[nf], 32);
    float vl = L1l[nf] + __shfl_xor(L1l[nf], 32);
    if (lane < 32) {
      atomicAdd(&Ss[nf*32 + lane], vs);
      atomicAdd(&L1s[nf*32 + lane], vl);
    }
  }
  __syncthreads();
  if (tid < BNK_) {
    size_t o = ((size_t)((t*WAY_ + way)*2 + kt))*QT_ + (size_t)pt*128 + tid;
    Spart[o] = Ss[tid]; L1part[o] = L1s[tid];
  }
}

// ---------------- K7: final score reduce -----------------------------------
__global__ __launch_bounds__(128) void k7_reduce(
    const float* __restrict__ Spart, const float* __restrict__ L1part,
    float* __restrict__ out) {
  int b = blockIdx.x;               // t*WQ+q
  int t = b / WQ_, q = b % WQ_;
  int tid = threadIdx.x;
  __shared__ float red[128];
  float contrib[WAY_] = {0,0,0,0,0};
  if (tid < HW_) {
    size_t p = (size_t)q*HW_ + tid;
    float l1 = 0.f;
#pragma unroll
    for (int w = 0; w < WAY_; ++w)
#pragma unroll
      for (int k = 0; k < 2; ++k)
        l1 += L1part[((size_t)((t*WAY_ + w)*2 + k))*QT_ + p];
    l1 = fmaxf(l1, 1e-12f);
#pragma unroll
    for (int w = 0; w < WAY_; ++w) {
      float sv = 0.f;
#pragma unroll
      for (int k = 0; k < 2; ++k)
        sv += Spart[((size_t)((t*WAY_ + w)*2 + k))*QT_ + p];
      contrib[w] = sv / l1;
    }
  }
#pragma unroll
  for (int w = 0; w < WAY_; ++w) {
    red[tid] = contrib[w];
    __syncthreads();
    for (int off = 64; off > 0; off >>= 1) {
      if (tid < off) red[tid] += red[tid + off];
      __syncthreads();
    }
    if (tid == 0) out[b*WAY_ + w] = red[0] * 30.f / (float)(HW_*5);
    __syncthreads();
  }
}

// ---------------- launch ----------------------------------------------------
extern "C" void kernel_launch(void* const* d_in, const int* in_sizes, int n_in,
                              void* d_out, int out_size, void* d_ws, size_t ws_size,
                              hipStream_t stream) {
  (void)in_sizes; (void)n_in; (void)out_size; (void)ws_size;
  const float* q  = (const float*)d_in[0];
  const float* s  = (const float*)d_in[1];
  const float* W  = (const float*)d_in[2];
  const float* g  = (const float*)d_in[3];
  const float* be = (const float*)d_in[4];
  const float* mu = (const float*)d_in[5];
  const float* va = (const float*)d_in[6];
  const float* w1 = (const float*)d_in[7];
  const float* b1 = (const float*)d_in[8];
  const float* w2 = (const float*)d_in[9];
  const float* b2 = (const float*)d_in[10];
  float* out = (float*)d_out;
  char* ws = (char*)d_ws;

  size_t off = 0;
  auto nxt = [&](size_t bytes) { size_t o = off; off += (bytes + 255) & ~(size_t)255; return o; };
  float* rq_inv = (float*)(ws + nxt((size_t)T_*QT_*4));
  float* rq_nrm = (float*)(ws + nxt((size_t)T_*QT_*4));
  float* rs_inv = (float*)(ws + nxt((size_t)T_*SP_*4));
  float* rs_nrm = (float*)(ws + nxt((size_t)T_*SP_*4));
  f16* Wr     = (f16*)(ws + nxt((size_t)C_*C_*2));
  f16* Wt8    = (f16*)(ws + nxt((size_t)C_*C_*2));
  f16* w1t    = (f16*)(ws + nxt((size_t)48*C_*2));
  f16* As_raw = (f16*)(ws + nxt((size_t)T_*KROWS_*C_*2));
  f16* As_emb = (f16*)(ws + nxt((size_t)T_*KROWS_*C_*2));
  f16* Bq_raw = (f16*)(ws + nxt((size_t)T_*C8_*QT_*8*2));
  f16* Bq_emb = (f16*)(ws + nxt((size_t)T_*C8_*QT_*8*2));
  float* cvp    = (float*)(ws + nxt((size_t)T_*QT_*4));
  float* invq   = (float*)(ws + nxt((size_t)T_*QT_*4));
  float* Spart  = (float*)(ws + nxt((size_t)T_*WAY_*2*QT_*4));
  float* L1part = (float*)(ws + nxt((size_t)T_*WAY_*2*QT_*4));

  ksetup<<<NB0_ + NBW_ + NBP_, 512, 0, stream>>>(
      q, s, W, w1, rq_inv, rq_nrm, rs_inv, rs_nrm, Wr, Wt8, w1t, Bq_raw, As_raw);
  k1_pack_qraw<<<T_*WQ_*10, 256, 0, stream>>>(q, rq_inv, Bq_raw);
  k2_pack_sraw<<<T_*WS_*10, 256, 0, stream>>>(s, rs_inv, As_raw);
  k3_embed_support<<<T_*(KROWS_/32), 512, 0, stream>>>(As_raw, Wt8, rs_nrm, g, be, mu, va, As_emb);
  k4_embed_query<<<T_*5*NPT_, 256, 0, stream>>>(Wr, Bq_raw, rq_nrm, g, be, mu, va, Bq_emb);
  k5_colnorm_psi<<<T_*NPT_, 256, 0, stream>>>(Bq_emb, w1t, b1, w2, b2, cvp, invq);
  k6_main<<<1200, 256, 0, stream>>>(As_emb, As_raw, Bq_emb, Bq_raw, cvp, invq, Spart, L1part);
  k7_reduce<<<T_*WQ_, 128, 0, stream>>>(Spart, L1part, out);
}